// Round 13
// baseline (171.085 us; speedup 1.0000x reference)
//
#include <hip/hip_runtime.h>
#include <hip/hip_bf16.h>

#define BB 32
#define NN 256
#define HH 768
#define NHEADS 12
#define DH 64
#define PHDIM 128
#define NVOCAB 35

typedef short bf16x8 __attribute__((ext_vector_type(8)));
typedef float f32x16 __attribute__((ext_vector_type(16)));
typedef unsigned u32x2 __attribute__((ext_vector_type(2)));

#define MFMA32 __builtin_amdgcn_mfma_f32_32x32x16_bf16

// round-to-nearest-even f32 -> bf16 bits
__device__ __forceinline__ unsigned short f2bf(float f) {
    unsigned u = __float_as_uint(f);
    unsigned r = (u + 0x7fffu + ((u >> 16) & 1u)) >> 16;
    return (unsigned short)r;
}

__device__ __forceinline__ float bf2f(unsigned short b) {
    return __uint_as_float(((unsigned)b) << 16);
}

__device__ __forceinline__ unsigned pk2(float a, float b) {
    return (unsigned)f2bf(a) | ((unsigned)f2bf(b) << 16);
}

__device__ __forceinline__ bf16x8 pack8(const float f[8]) {
    bf16x8 r;
#pragma unroll
    for (int e = 0; e < 8; ++e) r[e] = (short)f2bf(f[e]);
    return r;
}

// ---------------------------------------------------------------------------
// Kernel 0: fused prep (cast nodes, transpose weights, vocab tables)
// ---------------------------------------------------------------------------
__global__ __launch_bounds__(256) void k_prep(
        const float* __restrict__ nodes, unsigned short* __restrict__ nodes_bf,
        const float* __restrict__ Wq, const float* __restrict__ Wk,
        const float* __restrict__ Wv, const float* __restrict__ Wo,
        unsigned short* __restrict__ Wt,
        const float* __restrict__ pos_table,
        const float* __restrict__ g_path, const float* __restrict__ b_path,
        const float* __restrict__ Wsk, const float* __restrict__ bsk,
        const float* __restrict__ Wsv, const float* __restrict__ bsv,
        unsigned short* __restrict__ skv_bf, unsigned short* __restrict__ svv_t_bf) {
    const int blk = blockIdx.x;
    const int tid = threadIdx.x;

    if (blk < 6144) {
        int i = (blk * 256 + tid) * 4;
        float4 v = *reinterpret_cast<const float4*>(&nodes[i]);
        ushort4 o;
        o.x = f2bf(v.x); o.y = f2bf(v.y); o.z = f2bf(v.z); o.w = f2bf(v.w);
        *reinterpret_cast<ushort4*>(&nodes_bf[i]) = o;
        return;
    }

    if (blk < 6720) {
        __shared__ unsigned short tile[64][72];
        int wb = blk - 6144;
        int z = wb / 144;
        int rem = wb - z * 144;
        int k0 = (rem / 12) * 64, c0 = (rem % 12) * 64;
        const float* W = (z == 0) ? Wq : (z == 1) ? Wk : (z == 2) ? Wv : Wo;
        unsigned short* out = Wt + (size_t)z * HH * HH;
#pragma unroll
        for (int l = 0; l < 16; ++l) {
            int e = tid + l * 256;
            int r = e >> 6, c = e & 63;
            tile[c][r] = f2bf(W[(size_t)(k0 + r) * HH + c0 + c]);
        }
        __syncthreads();
#pragma unroll
        for (int l = 0; l < 2; ++l) {
            int e = tid + l * 256;
            int c = e >> 3, ch = e & 7;
            *reinterpret_cast<bf16x8*>(&out[(size_t)(c0 + c) * HH + k0 + ch * 8]) =
                *reinterpret_cast<const bf16x8*>(&tile[c][ch * 8]);
        }
        return;
    }

    // vocab
    {
        int v = blk - 6720;
        int t = tid;
        if (v >= NVOCAB) {
            if (t < 64) skv_bf[v * 64 + t] = 0;
            else if (t < 128 && v < 48) svv_t_bf[(t - 64) * 48 + v] = 0;
            return;
        }
        __shared__ float x[PHDIM];
        __shared__ float red[PHDIM];
        float xv = 0.f;
        if (t < PHDIM) { xv = pos_table[v * PHDIM + t]; red[t] = xv; }
        __syncthreads();
        for (int s = 64; s > 0; s >>= 1) { if (t < s) red[t] += red[t + s]; __syncthreads(); }
        float mean = red[0] / PHDIM;
        __syncthreads();
        if (t < PHDIM) { float c = xv - mean; red[t] = c * c; }
        __syncthreads();
        for (int s = 64; s > 0; s >>= 1) { if (t < s) red[t] += red[t + s]; __syncthreads(); }
        float var = red[0] / PHDIM;
        __syncthreads();
        if (t < PHDIM) x[t] = (xv - mean) * rsqrtf(var + 1e-5f) * g_path[t] + b_path[t];
        __syncthreads();
        if (t < 64) {
            float acc = bsk[t];
            for (int p = 0; p < PHDIM; ++p) acc += x[p] * Wsk[p * DH + t];
            skv_bf[v * 64 + t] = f2bf(acc);
        } else if (t < 128) {
            int d = t - 64;
            float acc = bsv[d];
            for (int p = 0; p < PHDIM; ++p) acc += x[p] * Wsv[p * DH + d];
            svv_t_bf[d * 48 + v] = f2bf(acc);
        }
    }
}

// ---------------------------------------------------------------------------
// Kernel 2: QKV MFMA GEMM -> fragment-order layouts; 1KB wave-burst stores.
// LDS union (34.8KB total) -> 4 blocks/CU.
// ---------------------------------------------------------------------------
__global__ __launch_bounds__(256, 4) void k_qkv(
        const unsigned short* __restrict__ Abf, const unsigned short* __restrict__ Wt,
        const float* __restrict__ bq, const float* __restrict__ bk, const float* __restrict__ bv,
        unsigned short* __restrict__ q_bf, unsigned short* __restrict__ k_bf,
        unsigned short* __restrict__ v_bf_t) {
    __shared__ __align__(16) char smem_raw[34816];
    unsigned short (*Al)[128 * 32] = reinterpret_cast<unsigned short(*)[128 * 32]>(smem_raw);
    unsigned short (*Bl)[128 * 32] = reinterpret_cast<unsigned short(*)[128 * 32]>(smem_raw + 16384);
    unsigned short (*vstage)[136]  = reinterpret_cast<unsigned short(*)[136]>(smem_raw);

    const int tid = threadIdx.x;
    const int w = tid >> 6, lane = tid & 63;
    const int il = lane & 31, hi = lane >> 5;
    const int wr = w >> 1, wc = w & 1;
    const int rowBase = blockIdx.x * 128;
    const int colBase = blockIdx.y * 128;
    const int sel = colBase / HH;
    const int jjBase0 = colBase - sel * HH;
    const float* bias = (sel == 0) ? bq : (sel == 1) ? bk : bv;

    f32x16 acc[2][2] = {};

    auto STAGE = [&](int buf, int k0) {
#pragma unroll
        for (int c = 0; c < 2; ++c) {
            int e = tid + c * 256;
            int row = e >> 2;
            int cb = (e & 3) << 4;
            int sc = cb ^ (((row >> 1) & 3) << 4);
            __builtin_amdgcn_global_load_lds(
                (const __attribute__((address_space(1))) unsigned int*)(Abf + (size_t)(rowBase + row) * HH + k0 + (sc >> 1)),
                (__attribute__((address_space(3))) unsigned int*)(&Al[buf][row * 32 + (cb >> 1)]), 16, 0, 0);
            __builtin_amdgcn_global_load_lds(
                (const __attribute__((address_space(1))) unsigned int*)(Wt + (size_t)(colBase + row) * HH + k0 + (sc >> 1)),
                (__attribute__((address_space(3))) unsigned int*)(&Bl[buf][row * 32 + (cb >> 1)]), 16, 0, 0);
        }
    };

    STAGE(0, 0);
    __syncthreads();
    for (int t = 0; t < 24; ++t) {
        int buf = t & 1;
        if (t < 23) STAGE(buf ^ 1, (t + 1) * 32);
#pragma unroll
        for (int ks = 0; ks < 2; ++ks) {
            bf16x8 af[2], bfr[2];
            int cb = (ks << 5) + (hi << 4);
#pragma unroll
            for (int t2 = 0; t2 < 2; ++t2) {
                int rrow = wr * 64 + t2 * 32 + il;
                af[t2] = *reinterpret_cast<const bf16x8*>(
                    &Al[buf][rrow * 32 + ((cb ^ (((rrow >> 1) & 3) << 4)) >> 1)]);
                int crow = wc * 64 + t2 * 32 + il;
                bfr[t2] = *reinterpret_cast<const bf16x8*>(
                    &Bl[buf][crow * 32 + ((cb ^ (((crow >> 1) & 3) << 4)) >> 1)]);
            }
            acc[0][0] = MFMA32(af[0], bfr[0], acc[0][0], 0, 0, 0);
            acc[0][1] = MFMA32(af[0], bfr[1], acc[0][1], 0, 0, 0);
            acc[1][0] = MFMA32(af[1], bfr[0], acc[1][0], 0, 0, 0);
            acc[1][1] = MFMA32(af[1], bfr[1], acc[1][1], 0, 0, 0);
        }
        __syncthreads();   // also fences DS reads before the aliased epilogue
    }

    if (sel < 2) {
        unsigned short* outp = (sel == 0) ? q_bf : k_bf;
        float scale = (sel == 0) ? 0.125f : 1.0f;
        unsigned short* qst = &vstage[0][0];   // per-wave slice [w][32][34] (aliased LDS)
        const int b = rowBase >> 8;
        const int hB = jjBase0 >> 6;
#pragma unroll
        for (int rt = 0; rt < 2; ++rt)
#pragma unroll
            for (int ct = 0; ct < 2; ++ct) {
                int jjB = jjBase0 + wc * 64 + ct * 32;
                float bias_v = bias[jjB + il];
#pragma unroll
                for (int r = 0; r < 16; ++r) {
                    int ir = (r & 3) + 8 * (r >> 2) + 4 * hi;
                    qst[(w * 32 + ir) * 34 + il] = f2bf((acc[rt][ct][r] + bias_v) * scale);
                }
                int R0 = rowBase + wr * 64 + rt * 32;
                int t32 = (R0 & 255) >> 5;
                int bh = b * NHEADS + hB + wc;
#pragma unroll
                for (int g = 0; g < 2; ++g) {
                    int kt = ct * 2 + g;
                    size_t base = ((size_t)(bh * 8 + t32) * 4 + kt) * 512;
                    bf16x8 vv = *reinterpret_cast<const bf16x8*>(
                        &qst[(w * 32 + (lane & 31)) * 34 + g * 16 + (lane >> 5) * 8]);
                    *reinterpret_cast<bf16x8*>(&outp[base + lane * 8]) = vv;   // 1KB/wave
                }
            }
    } else {
#pragma unroll
        for (int rt = 0; rt < 2; ++rt)
#pragma unroll
            for (int ct = 0; ct < 2; ++ct) {
                int jjB = jjBase0 + wc * 64 + ct * 32;
                float bias_v = bias[jjB + il];
#pragma unroll
                for (int r = 0; r < 16; ++r) {
                    int rl = wr * 64 + rt * 32 + ((r & 3) + 8 * (r >> 2) + 4 * hi);
                    vstage[wc * 64 + ct * 32 + il][rl] = f2bf(acc[rt][ct][r] + bias_v);
                }
            }
        __syncthreads();
        int b = rowBase >> 8, n0 = rowBase & 255;
        int h0v = jjBase0 >> 6;
#pragma unroll
        for (int q = 0; q < 8; ++q) {
            int rid = w * 8 + q;            // head(2) x jtl(4) x ks(2) x dh(2)
            int head = rid >> 4, jtl = (rid >> 2) & 3, ks = (rid >> 1) & 1, dh = rid & 1;
            int bh = b * NHEADS + h0v + head;
            int jtg = (n0 >> 5) + jtl;
            size_t base = ((((size_t)(bh * 8 + jtg) * 2 + ks) * 2 + dh) * 64) * 8;
            bf16x8 vv = *reinterpret_cast<const bf16x8*>(
                &vstage[head * 64 + dh * 32 + (lane & 31)][jtl * 32 + ks * 16 + (lane >> 5) * 8]);
            *reinterpret_cast<bf16x8*>(&v_bf_t[base + lane * 8]) = vv;   // 1KB/wave
        }
    }
}

// ---------------------------------------------------------------------------
// Kernel 3: MFMA attention, 4-way j-split, coalesced fragment loads, setprio.
// oex packed bf16 (13.5KB) -> LDS 26.0KB -> 6 blocks/CU @ launch_bounds(256,6).
// grid = 3072 (bh x 8 rowblocks, XCD-chunked), 3 barriers.
// ---------------------------------------------------------------------------
__global__ __launch_bounds__(256, 6) void k_attn(
        const unsigned short* __restrict__ q_bf, const unsigned short* __restrict__ k_bf,
        const unsigned short* __restrict__ v_bf_t,
        const unsigned short* __restrict__ skv_bf, const unsigned short* __restrict__ svv_t_bf,
        const float* __restrict__ bias,
        float* __restrict__ wout, unsigned short* __restrict__ attn_out) {
    __shared__ __align__(16) float qs_s[32][36];
    __shared__ __align__(16) float wsum[32][48];
    __shared__ __align__(8) unsigned oex[3][32][36];   // packed bf16 O partials
    __shared__ float msum[4][32][2];
    __shared__ float bias_s[NN];

    const int bx0 = blockIdx.x;
    const int bx = (bx0 & 7) * 384 + (bx0 >> 3);    // XCD-chunked
    const int bh = bx >> 3, rowblk = bx & 7;
    const int b = bh / NHEADS, h = bh - b * NHEADS;
    const int tid = threadIdx.x;
    const int w = tid >> 6, lane = tid & 63;
    const int il = lane & 31, hi = lane >> 5;
    const int i0 = rowblk * 32;
    const int ig = i0 + il;

    bias_s[tid] = bias[b * NN + tid];
#pragma unroll
    for (int z = 0; z < 6; ++z) ((float*)wsum)[tid + z * 256] = 0.f;

    // Q fragments (coalesced: base + lane*16B)
    bf16x8 qf[4];
#pragma unroll
    for (int kt = 0; kt < 4; ++kt)
        qf[kt] = *reinterpret_cast<const bf16x8*>(
            &q_bf[((((size_t)bh * 8 + rowblk) * 4 + kt) * 64 + lane) * 8]);

    // qs = Q @ skv^T, wave 0 only
    if (w == 0) {
        f32x16 qa0 = {}, qa1 = {};
#pragma unroll
        for (int kt = 0; kt < 4; ++kt) {
            bf16x8 s0 = *reinterpret_cast<const bf16x8*>(&skv_bf[(size_t)il * 64 + kt * 16 + 8 * hi]);
            bf16x8 s1 = *reinterpret_cast<const bf16x8*>(&skv_bf[(size_t)(32 + il) * 64 + kt * 16 + 8 * hi]);
            qa0 = MFMA32(qf[kt], s0, qa0, 0, 0, 0);
            qa1 = MFMA32(qf[kt], s1, qa1, 0, 0, 0);
        }
#pragma unroll
        for (int r = 0; r < 16; ++r) {
            int ir = (r & 3) + 8 * (r >> 2) + 4 * hi;
            qs_s[ir][il] = qa0[r];
            if (il < 3) qs_s[ir][32 + il] = qa1[r];
        }
    }

    // QK^T for this wave's 64-j strip (coalesced K loads)
    f32x16 S[2] = {};
    __builtin_amdgcn_s_setprio(1);
#pragma unroll
    for (int jt = 0; jt < 2; ++jt) {
        int jtg = w * 2 + jt;
#pragma unroll
        for (int kt = 0; kt < 4; ++kt) {
            bf16x8 kf = *reinterpret_cast<const bf16x8*>(
                &k_bf[((((size_t)bh * 8 + jtg) * 4 + kt) * 64 + lane) * 8]);
            S[jt] = MFMA32(kf, qf[kt], S[jt], 0, 0, 0);
        }
    }
    __builtin_amdgcn_s_setprio(0);

    __syncthreads();   // b1: bias, qs, zeroed wsum ready

    const int jb = w * 64;
    // add struct_w (clamped qs lookup) + bias
    {
        float qlo = qs_s[il][0], qhi = qs_s[il][34];
#pragma unroll
        for (int jt = 0; jt < 2; ++jt) {
#pragma unroll
            for (int rg = 0; rg < 4; ++rg) {
                int j0 = jb + jt * 32 + rg * 8 + 4 * hi;
                float4 bv4 = *reinterpret_cast<const float4*>(&bias_s[j0]);
                float bvf[4] = {bv4.x, bv4.y, bv4.z, bv4.w};
#pragma unroll
                for (int e = 0; e < 4; ++e) {
                    int dd = j0 + e - ig;
                    float sw = (dd < -16) ? qlo : (dd > 16) ? qhi : qs_s[il][dd + 17];
                    S[jt][rg * 4 + e] += bvf[e] + sw;
                }
            }
        }
    }

    // partial softmax over this j-strip (row split lane/lane^32)
    float m = -3.4e38f;
#pragma unroll
    for (int jt = 0; jt < 2; ++jt)
#pragma unroll
        for (int r = 0; r < 16; ++r) m = fmaxf(m, S[jt][r]);
    m = fmaxf(m, __shfl_xor(m, 32));
    float sum = 0.f;
#pragma unroll
    for (int jt = 0; jt < 2; ++jt)
#pragma unroll
        for (int r = 0; r < 16; ++r) { float p = __expf(S[jt][r] - m); S[jt][r] = p; sum += p; }
    sum += __shfl_xor(sum, 32);
    if (hi == 0) { msum[w][il][0] = m; msum[w][il][1] = sum; }
    __syncthreads();   // b2: all partial (m,sum) ready

    {
        float m0 = msum[0][il][0], m1 = msum[1][il][0];
        float m2 = msum[2][il][0], m3 = msum[3][il][0];
        float M = fmaxf(fmaxf(m0, m1), fmaxf(m2, m3));
        float sumT = msum[0][il][1] * __expf(m0 - M) + msum[1][il][1] * __expf(m1 - M) +
                     msum[2][il][1] * __expf(m2 - M) + msum[3][il][1] * __expf(m3 - M);
        float scale = __expf(m - M) / sumT;
#pragma unroll
        for (int jt = 0; jt < 2; ++jt)
#pragma unroll
            for (int r = 0; r < 16; ++r) S[jt][r] *= scale;
    }

    // histogram scatter
    {
        float elo = 0.f, ehi = 0.f;
#pragma unroll
        for (int jt = 0; jt < 2; ++jt)
#pragma unroll
            for (int r = 0; r < 16; ++r) {
                int j = jb + jt * 32 + (r & 3) + 8 * (r >> 2) + 4 * hi;
                int dd = j - ig;
                float p = S[jt][r];
                if (dd < -16) elo += p;
                else if (dd > 16) ehi += p;
                else wsum[il][dd + 17] = p;
            }
        if (elo != 0.f) atomicAdd(&wsum[il][0], elo);
        if (ehi != 0.f) atomicAdd(&wsum[il][34], ehi);
    }

    // main PV (O^T) from regs (coalesced V loads)
    f32x16 O0 = {}, O1 = {};
    __builtin_amdgcn_s_setprio(1);
#pragma unroll
    for (int jt = 0; jt < 2; ++jt) {
        int jtg = w * 2 + jt;
#pragma unroll
        for (int ks = 0; ks < 2; ++ks) {
            unsigned w0 = pk2(S[jt][8 * ks + 0], S[jt][8 * ks + 1]);
            unsigned w1 = pk2(S[jt][8 * ks + 2], S[jt][8 * ks + 3]);
            unsigned w2 = pk2(S[jt][8 * ks + 4], S[jt][8 * ks + 5]);
            unsigned w3 = pk2(S[jt][8 * ks + 6], S[jt][8 * ks + 7]);
            unsigned s0 = hi ? w0 : w2, s1 = hi ? w1 : w3;
            unsigned y0 = (unsigned)__shfl_xor((int)s0, 32);
            unsigned y1 = (unsigned)__shfl_xor((int)s1, 32);
            union { bf16x8 v; unsigned u[4]; } Bf;
            Bf.u[0] = hi ? y0 : w0;
            Bf.u[1] = hi ? y1 : w1;
            Bf.u[2] = hi ? w2 : y0;
            Bf.u[3] = hi ? w3 : y1;
            bf16x8 va0 = *reinterpret_cast<const bf16x8*>(
                &v_bf_t[(((((size_t)bh * 8 + jtg) * 2 + ks) * 2 + 0) * 64 + lane) * 8]);
            bf16x8 va1 = *reinterpret_cast<const bf16x8*>(
                &v_bf_t[(((((size_t)bh * 8 + jtg) * 2 + ks) * 2 + 1) * 64 + lane) * 8]);
            O0 = MFMA32(va0, Bf.v, O0, 0, 0, 0);
            O1 = MFMA32(va1, Bf.v, O1, 0, 0, 0);
        }
    }
    __builtin_amdgcn_s_setprio(0);

    // w-write: direct f32 from S regs (after PV so V loads issue early)
#pragma unroll
    for (int jt = 0; jt < 2; ++jt) {
#pragma unroll
        for (int rg = 0; rg < 4; ++rg) {
            float4 val;
            val.x = S[jt][rg * 4 + 0];
            val.y = S[jt][rg * 4 + 1];
            val.z = S[jt][rg * 4 + 2];
            val.w = S[jt][rg * 4 + 3];
            *reinterpret_cast<float4*>(
                &wout[((size_t)(bh * NN + ig)) * NN + jb + jt * 32 + rg * 8 + 4 * hi]) = val;
        }
    }

    // waves 1-3: write partial O (packed bf16) to private slice
    if (w != 0) {
#pragma unroll
        for (int qq = 0; qq < 4; ++qq) {
            int d0 = 8 * qq + 4 * hi;
            u32x2 p0, p1;
            p0[0] = pk2(O0[4 * qq + 0], O0[4 * qq + 1]);
            p0[1] = pk2(O0[4 * qq + 2], O0[4 * qq + 3]);
            p1[0] = pk2(O1[4 * qq + 0], O1[4 * qq + 1]);
            p1[1] = pk2(O1[4 * qq + 2], O1[4 * qq + 3]);
            *reinterpret_cast<u32x2*>(&oex[w - 1][il][d0 >> 1]) = p0;
            *reinterpret_cast<u32x2*>(&oex[w - 1][il][(32 + d0) >> 1]) = p1;
        }
    }
    __syncthreads();   // b3: histogram + O partials complete

    if (w == 0) {
#pragma unroll
        for (int s = 0; s < 3; ++s) {
#pragma unroll
            for (int qq = 0; qq < 4; ++qq) {
                int d0 = 8 * qq + 4 * hi;
                u32x2 p0 = *reinterpret_cast<const u32x2*>(&oex[s][il][d0 >> 1]);
                u32x2 p1 = *reinterpret_cast<const u32x2*>(&oex[s][il][(32 + d0) >> 1]);
                O0[4 * qq + 0] += __uint_as_float((p0[0] & 0xffffu) << 16);
                O0[4 * qq + 1] += __uint_as_float(p0[0] & 0xffff0000u);
                O0[4 * qq + 2] += __uint_as_float((p0[1] & 0xffffu) << 16);
                O0[4 * qq + 3] += __uint_as_float(p0[1] & 0xffff0000u);
                O1[4 * qq + 0] += __uint_as_float((p1[0] & 0xffffu) << 16);
                O1[4 * qq + 1] += __uint_as_float(p1[0] & 0xffff0000u);
                O1[4 * qq + 2] += __uint_as_float((p1[1] & 0xffffu) << 16);
                O1[4 * qq + 3] += __uint_as_float(p1[1] & 0xffff0000u);
            }
        }

        // struct-PV: O^T += svv^T @ wsum^T
#pragma unroll
        for (int kt = 0; kt < 3; ++kt) {
            float4 a0 = *reinterpret_cast<const float4*>(&wsum[il][kt * 16 + 8 * hi]);
            float4 a1 = *reinterpret_cast<const float4*>(&wsum[il][kt * 16 + 8 * hi + 4]);
            float af[8] = {a0.x, a0.y, a0.z, a0.w, a1.x, a1.y, a1.z, a1.w};
            bf16x8 Bf = pack8(af);
            bf16x8 sa0 = *reinterpret_cast<const bf16x8*>(&svv_t_bf[(size_t)il * 48 + kt * 16 + 8 * hi]);
            bf16x8 sa1 = *reinterpret_cast<const bf16x8*>(&svv_t_bf[(size_t)(32 + il) * 48 + kt * 16 + 8 * hi]);
            O0 = MFMA32(sa0, Bf, O0, 0, 0, 0);
            O1 = MFMA32(sa1, Bf, O1, 0, 0, 0);
        }

        // attn_out (bf16): lane owns row i0+il, regs span d
#pragma unroll
        for (int qq = 0; qq < 4; ++qq) {
            int d0 = 8 * qq + 4 * hi;
            u32x2 o0, o1;
            o0[0] = pk2(O0[4 * qq + 0], O0[4 * qq + 1]);
            o0[1] = pk2(O0[4 * qq + 2], O0[4 * qq + 3]);
            o1[0] = pk2(O1[4 * qq + 0], O1[4 * qq + 1]);
            o1[1] = pk2(O1[4 * qq + 2], O1[4 * qq + 3]);
            size_t base = ((size_t)(b * NN + i0 + il)) * HH + h * 64;
            *reinterpret_cast<u32x2*>(&attn_out[base + d0]) = o0;
            *reinterpret_cast<u32x2*>(&attn_out[base + 32 + d0]) = o1;
        }
    }
}

// ---------------------------------------------------------------------------
// Kernel 4: O-projection MFMA GEMM + bias + relu -> bf16
// ---------------------------------------------------------------------------
__global__ __launch_bounds__(256) void k_ogemm(
        const unsigned short* __restrict__ Abf, const unsigned short* __restrict__ Bt,
        const float* __restrict__ bo, unsigned short* __restrict__ Cout) {
    __shared__ unsigned short Al[2][128 * 32];
    __shared__ unsigned short Bl[2][128 * 32];

    const int tid = threadIdx.x;
    const int w = tid >> 6, lane = tid & 63;
    const int il = lane & 31, hi = lane >> 5;
    const int wr = w >> 1, wc = w & 1;
    const int rowBase = blockIdx.x * 128;
    const int colBase = blockIdx.y * 128;

    f32x16 acc[2][2] = {};

    auto STAGE = [&](int buf, int k0) {
#pragma unroll
        for (int c = 0; c < 2; ++c) {
            int e = tid + c * 256;
            int row = e >> 2;
            int cb = (e & 3) << 4;
            int sc = cb ^ (((row >> 1) & 3) << 4);
            __builtin_amdgcn_global_load_lds(
                (const __attribute__((address_space(1))) unsigned int*)(Abf + (size_t)(rowBase + row) * HH + k0 + (sc >> 1)),
                (__attribute__((address_space(3))) unsigned int*)(&Al[buf][row * 32 + (cb >> 1)]), 16, 0, 0);
            __builtin_amdgcn_global_load_lds(
                (const __attribute__((address_space(1))) unsigned int*)(Bt + (size_t)(colBase + row) * HH + k0 + (sc >> 1)),
                (__attribute__((address_space(3))) unsigned int*)(&Bl[buf][row * 32 + (cb >> 1)]), 16, 0, 0);
        }
    };

    STAGE(0, 0);
    __syncthreads();
    for (int t = 0; t < 24; ++t) {
        int buf = t & 1;
        if (t < 23) STAGE(buf ^ 1, (t + 1) * 32);
#pragma unroll
        for (int ks = 0; ks < 2; ++ks) {
            bf16x8 af[2], bfr[2];
            int cb = (ks << 5) + (hi << 4);
#pragma unroll
            for (int t2 = 0; t2 < 2; ++t2) {
                int rrow = wr * 64 + t2 * 32 + il;
                af[t2] = *reinterpret_cast<const bf16x8*>(
                    &Al[buf][rrow * 32 + ((cb ^ (((rrow >> 1) & 3) << 4)) >> 1)]);
                int crow = wc * 64 + t2 * 32 + il;
                bfr[t2] = *reinterpret_cast<const bf16x8*>(
                    &Bl[buf][crow * 32 + ((cb ^ (((crow >> 1) & 3) << 4)) >> 1)]);
            }
            acc[0][0] = MFMA32(af[0], bfr[0], acc[0][0], 0, 0, 0);
            acc[0][1] = MFMA32(af[0], bfr[1], acc[0][1], 0, 0, 0);
            acc[1][0] = MFMA32(af[1], bfr[0], acc[1][0], 0, 0, 0);
            acc[1][1] = MFMA32(af[1], bfr[1], acc[1][1], 0, 0, 0);
        }
        __syncthreads();
    }

#pragma unroll
    for (int rt = 0; rt < 2; ++rt)
#pragma unroll
        for (int ct = 0; ct < 2; ++ct) {
            int col = colBase + wc * 64 + ct * 32 + il;
            float bias_v = bo[col];
#pragma unroll
            for (int r = 0; r < 16; ++r) {
                int row = rowBase + wr * 64 + rt * 32 + ((r & 3) + 8 * (r >> 2) + 4 * hi);
                Cout[(size_t)row * HH + col] = f2bf(fmaxf(acc[rt][ct][r] + bias_v, 0.f));
            }
        }
}

// ---------------------------------------------------------------------------
// Kernel 5: final LayerNorm(nodes_bf16 + proj_bf16), single-pass + shfl
// ---------------------------------------------------------------------------
__global__ __launch_bounds__(256) void k_ln(
        const unsigned short* __restrict__ nodes_bf, const unsigned short* __restrict__ proj,
        const float* __restrict__ g, const float* __restrict__ bta,
        float* __restrict__ out) {
    __shared__ float red[2][4];
    int row = blockIdx.x;
    int tid = threadIdx.x;
    int w = tid >> 6, lane = tid & 63;
    float x[3];
    float s = 0.f, s2 = 0.f;
#pragma unroll
    for (int l = 0; l < 3; ++l) {
        int c = tid + l * 256;
        x[l] = bf2f(nodes_bf[(size_t)row * HH + c]) + bf2f(proj[(size_t)row * HH + c]);
        s += x[l];
        s2 += x[l] * x[l];
    }
#pragma unroll
    for (int off = 32; off > 0; off >>= 1) {
        s += __shfl_xor(s, off);
        s2 += __shfl_xor(s2, off);
    }
    if (lane == 0) { red[0][w] = s; red[1][w] = s2; }
    __syncthreads();
    float ts = red[0][0] + red[0][1] + red[0][2] + red[0][3];
    float ts2 = red[1][0] + red[1][1] + red[1][2] + red[1][3];
    float mean = ts / HH;
    float var = ts2 / HH - mean * mean;
    float inv = rsqrtf(fmaxf(var, 0.f) + 1e-5f);
#pragma unroll
    for (int l = 0; l < 3; ++l) {
        int c = tid + l * 256;
        out[(size_t)row * HH + c] = (x[l] - mean) * inv * g[c] + bta[c];
    }
}

// ---------------------------------------------------------------------------
extern "C" void kernel_launch(void* const* d_in, const int* in_sizes, int n_in,
                              void* d_out, int out_size, void* d_ws, size_t ws_size,
                              hipStream_t stream) {
    const float* nodes     = (const float*)d_in[0];
    const float* bias      = (const float*)d_in[1];
    const float* pos_table = (const float*)d_in[3];
    const float* Wq = (const float*)d_in[4];  const float* bq = (const float*)d_in[5];
    const float* Wk = (const float*)d_in[6];  const float* bk = (const float*)d_in[7];
    const float* Wv = (const float*)d_in[8];  const float* bv = (const float*)d_in[9];
    const float* Wsk = (const float*)d_in[10]; const float* bsk = (const float*)d_in[11];
    const float* Wsv = (const float*)d_in[12]; const float* bsv = (const float*)d_in[13];
    const float* Wo = (const float*)d_in[14]; const float* bo = (const float*)d_in[15];
    const float* g_path = (const float*)d_in[16]; const float* b_path = (const float*)d_in[17];
    const float* g_norm = (const float*)d_in[18]; const float* b_norm = (const float*)d_in[19];

    float* out0 = (float*)d_out;                         // (B,N,H)
    float* wout = out0 + (size_t)BB * NN * HH;           // (B,HEADS,N,N)

    const size_t per = (size_t)BB * NN * HH;             // 6,291,456 elements
    char* p = (char*)d_ws;
    unsigned short* q_bf    = (unsigned short*)p; p += per * 2;
    unsigned short* k_bf    = (unsigned short*)p; p += per * 2;
    unsigned short* v_bf_t  = (unsigned short*)p; p += per * 2;
    unsigned short* skv_bf  = (unsigned short*)p; p += 64 * 64 * 2;
    unsigned short* svv_t   = (unsigned short*)p; p += 64 * 48 * 2;
    unsigned short* nodes_bf= (unsigned short*)p; p += per * 2;
    unsigned short* Wt      = (unsigned short*)p; p += (size_t)4 * HH * HH * 2;
    unsigned short* attn_bf = (unsigned short*)p; p += per * 2;
    unsigned short* proj_bf = v_bf_t;   // Vf dead after k_attn

    k_prep<<<6784, 256, 0, stream>>>(nodes, nodes_bf, Wq, Wk, Wv, Wo, Wt,
                                     pos_table, g_path, b_path, Wsk, bsk, Wsv, bsv,
                                     skv_bf, svv_t);

    dim3 g2(64, 18);
    k_qkv<<<g2, 256, 0, stream>>>(nodes_bf, Wt, bq, bk, bv, q_bf, k_bf, v_bf_t);

    k_attn<<<BB * NHEADS * 8, 256, 0, stream>>>(q_bf, k_bf, v_bf_t, skv_bf, svv_t, bias, wout, attn_bf);

    dim3 g4(64, 6);
    k_ogemm<<<g4, 256, 0, stream>>>(attn_bf, Wt + (size_t)3 * HH * HH, bo, proj_bf);

    k_ln<<<BB * NN, 256, 0, stream>>>(nodes_bf, proj_bf, g_norm, b_norm, out0);
}

// Round 14
// 130.976 us; speedup vs baseline: 1.3062x; 1.3062x over previous
//
#include <hip/hip_runtime.h>
#include <hip/hip_bf16.h>

#define BB 32
#define NN 256
#define HH 768
#define NHEADS 12
#define DH 64
#define PHDIM 128
#define NVOCAB 35

typedef short bf16x8 __attribute__((ext_vector_type(8)));
typedef float f32x16 __attribute__((ext_vector_type(16)));
typedef unsigned u32x2 __attribute__((ext_vector_type(2)));

#define MFMA32 __builtin_amdgcn_mfma_f32_32x32x16_bf16

// round-to-nearest-even f32 -> bf16 bits
__device__ __forceinline__ unsigned short f2bf(float f) {
    unsigned u = __float_as_uint(f);
    unsigned r = (u + 0x7fffu + ((u >> 16) & 1u)) >> 16;
    return (unsigned short)r;
}

__device__ __forceinline__ float bf2f(unsigned short b) {
    return __uint_as_float(((unsigned)b) << 16);
}

__device__ __forceinline__ unsigned pk2(float a, float b) {
    return (unsigned)f2bf(a) | ((unsigned)f2bf(b) << 16);
}

__device__ __forceinline__ bf16x8 pack8(const float f[8]) {
    bf16x8 r;
#pragma unroll
    for (int e = 0; e < 8; ++e) r[e] = (short)f2bf(f[e]);
    return r;
}

// ---------------------------------------------------------------------------
// Kernel 0: fused prep (cast nodes, transpose weights, vocab tables)
// ---------------------------------------------------------------------------
__global__ __launch_bounds__(256) void k_prep(
        const float* __restrict__ nodes, unsigned short* __restrict__ nodes_bf,
        const float* __restrict__ Wq, const float* __restrict__ Wk,
        const float* __restrict__ Wv, const float* __restrict__ Wo,
        unsigned short* __restrict__ Wt,
        const float* __restrict__ pos_table,
        const float* __restrict__ g_path, const float* __restrict__ b_path,
        const float* __restrict__ Wsk, const float* __restrict__ bsk,
        const float* __restrict__ Wsv, const float* __restrict__ bsv,
        unsigned short* __restrict__ skv_bf, unsigned short* __restrict__ svv_t_bf) {
    const int blk = blockIdx.x;
    const int tid = threadIdx.x;

    if (blk < 6144) {
        int i = (blk * 256 + tid) * 4;
        float4 v = *reinterpret_cast<const float4*>(&nodes[i]);
        ushort4 o;
        o.x = f2bf(v.x); o.y = f2bf(v.y); o.z = f2bf(v.z); o.w = f2bf(v.w);
        *reinterpret_cast<ushort4*>(&nodes_bf[i]) = o;
        return;
    }

    if (blk < 6720) {
        __shared__ unsigned short tile[64][72];
        int wb = blk - 6144;
        int z = wb / 144;
        int rem = wb - z * 144;
        int k0 = (rem / 12) * 64, c0 = (rem % 12) * 64;
        const float* W = (z == 0) ? Wq : (z == 1) ? Wk : (z == 2) ? Wv : Wo;
        unsigned short* out = Wt + (size_t)z * HH * HH;
#pragma unroll
        for (int l = 0; l < 16; ++l) {
            int e = tid + l * 256;
            int r = e >> 6, c = e & 63;
            tile[c][r] = f2bf(W[(size_t)(k0 + r) * HH + c0 + c]);
        }
        __syncthreads();
#pragma unroll
        for (int l = 0; l < 2; ++l) {
            int e = tid + l * 256;
            int c = e >> 3, ch = e & 7;
            *reinterpret_cast<bf16x8*>(&out[(size_t)(c0 + c) * HH + k0 + ch * 8]) =
                *reinterpret_cast<const bf16x8*>(&tile[c][ch * 8]);
        }
        return;
    }

    // vocab
    {
        int v = blk - 6720;
        int t = tid;
        if (v >= NVOCAB) {
            if (t < 64) skv_bf[v * 64 + t] = 0;
            else if (t < 128 && v < 48) svv_t_bf[(t - 64) * 48 + v] = 0;
            return;
        }
        __shared__ float x[PHDIM];
        __shared__ float red[PHDIM];
        float xv = 0.f;
        if (t < PHDIM) { xv = pos_table[v * PHDIM + t]; red[t] = xv; }
        __syncthreads();
        for (int s = 64; s > 0; s >>= 1) { if (t < s) red[t] += red[t + s]; __syncthreads(); }
        float mean = red[0] / PHDIM;
        __syncthreads();
        if (t < PHDIM) { float c = xv - mean; red[t] = c * c; }
        __syncthreads();
        for (int s = 64; s > 0; s >>= 1) { if (t < s) red[t] += red[t + s]; __syncthreads(); }
        float var = red[0] / PHDIM;
        __syncthreads();
        if (t < PHDIM) x[t] = (xv - mean) * rsqrtf(var + 1e-5f) * g_path[t] + b_path[t];
        __syncthreads();
        if (t < 64) {
            float acc = bsk[t];
            for (int p = 0; p < PHDIM; ++p) acc += x[p] * Wsk[p * DH + t];
            skv_bf[v * 64 + t] = f2bf(acc);
        } else if (t < 128) {
            int d = t - 64;
            float acc = bsv[d];
            for (int p = 0; p < PHDIM; ++p) acc += x[p] * Wsv[p * DH + d];
            svv_t_bf[d * 48 + v] = f2bf(acc);
        }
    }
}

// ---------------------------------------------------------------------------
// Kernel 2: QKV MFMA GEMM -> fragment-order layouts; 1KB wave-burst stores.
// LDS union (34.8KB total) -> 4 blocks/CU.
// ---------------------------------------------------------------------------
__global__ __launch_bounds__(256, 4) void k_qkv(
        const unsigned short* __restrict__ Abf, const unsigned short* __restrict__ Wt,
        const float* __restrict__ bq, const float* __restrict__ bk, const float* __restrict__ bv,
        unsigned short* __restrict__ q_bf, unsigned short* __restrict__ k_bf,
        unsigned short* __restrict__ v_bf_t) {
    __shared__ __align__(16) char smem_raw[34816];
    unsigned short (*Al)[128 * 32] = reinterpret_cast<unsigned short(*)[128 * 32]>(smem_raw);
    unsigned short (*Bl)[128 * 32] = reinterpret_cast<unsigned short(*)[128 * 32]>(smem_raw + 16384);
    unsigned short (*vstage)[136]  = reinterpret_cast<unsigned short(*)[136]>(smem_raw);

    const int tid = threadIdx.x;
    const int w = tid >> 6, lane = tid & 63;
    const int il = lane & 31, hi = lane >> 5;
    const int wr = w >> 1, wc = w & 1;
    const int rowBase = blockIdx.x * 128;
    const int colBase = blockIdx.y * 128;
    const int sel = colBase / HH;
    const int jjBase0 = colBase - sel * HH;
    const float* bias = (sel == 0) ? bq : (sel == 1) ? bk : bv;

    f32x16 acc[2][2] = {};

    auto STAGE = [&](int buf, int k0) {
#pragma unroll
        for (int c = 0; c < 2; ++c) {
            int e = tid + c * 256;
            int row = e >> 2;
            int cb = (e & 3) << 4;
            int sc = cb ^ (((row >> 1) & 3) << 4);
            __builtin_amdgcn_global_load_lds(
                (const __attribute__((address_space(1))) unsigned int*)(Abf + (size_t)(rowBase + row) * HH + k0 + (sc >> 1)),
                (__attribute__((address_space(3))) unsigned int*)(&Al[buf][row * 32 + (cb >> 1)]), 16, 0, 0);
            __builtin_amdgcn_global_load_lds(
                (const __attribute__((address_space(1))) unsigned int*)(Wt + (size_t)(colBase + row) * HH + k0 + (sc >> 1)),
                (__attribute__((address_space(3))) unsigned int*)(&Bl[buf][row * 32 + (cb >> 1)]), 16, 0, 0);
        }
    };

    STAGE(0, 0);
    __syncthreads();
    for (int t = 0; t < 24; ++t) {
        int buf = t & 1;
        if (t < 23) STAGE(buf ^ 1, (t + 1) * 32);
#pragma unroll
        for (int ks = 0; ks < 2; ++ks) {
            bf16x8 af[2], bfr[2];
            int cb = (ks << 5) + (hi << 4);
#pragma unroll
            for (int t2 = 0; t2 < 2; ++t2) {
                int rrow = wr * 64 + t2 * 32 + il;
                af[t2] = *reinterpret_cast<const bf16x8*>(
                    &Al[buf][rrow * 32 + ((cb ^ (((rrow >> 1) & 3) << 4)) >> 1)]);
                int crow = wc * 64 + t2 * 32 + il;
                bfr[t2] = *reinterpret_cast<const bf16x8*>(
                    &Bl[buf][crow * 32 + ((cb ^ (((crow >> 1) & 3) << 4)) >> 1)]);
            }
            acc[0][0] = MFMA32(af[0], bfr[0], acc[0][0], 0, 0, 0);
            acc[0][1] = MFMA32(af[0], bfr[1], acc[0][1], 0, 0, 0);
            acc[1][0] = MFMA32(af[1], bfr[0], acc[1][0], 0, 0, 0);
            acc[1][1] = MFMA32(af[1], bfr[1], acc[1][1], 0, 0, 0);
        }
        __syncthreads();   // also fences DS reads before the aliased epilogue
    }

    if (sel < 2) {
        unsigned short* outp = (sel == 0) ? q_bf : k_bf;
        float scale = (sel == 0) ? 0.125f : 1.0f;
        unsigned short* qst = &vstage[0][0];   // per-wave slice [w][32][34] (aliased LDS)
        const int b = rowBase >> 8;
        const int hB = jjBase0 >> 6;
#pragma unroll
        for (int rt = 0; rt < 2; ++rt)
#pragma unroll
            for (int ct = 0; ct < 2; ++ct) {
                int jjB = jjBase0 + wc * 64 + ct * 32;
                float bias_v = bias[jjB + il];
#pragma unroll
                for (int r = 0; r < 16; ++r) {
                    int ir = (r & 3) + 8 * (r >> 2) + 4 * hi;
                    qst[(w * 32 + ir) * 34 + il] = f2bf((acc[rt][ct][r] + bias_v) * scale);
                }
                int R0 = rowBase + wr * 64 + rt * 32;
                int t32 = (R0 & 255) >> 5;
                int bh = b * NHEADS + hB + wc;
#pragma unroll
                for (int g = 0; g < 2; ++g) {
                    int kt = ct * 2 + g;
                    size_t base = ((size_t)(bh * 8 + t32) * 4 + kt) * 512;
                    bf16x8 vv = *reinterpret_cast<const bf16x8*>(
                        &qst[(w * 32 + (lane & 31)) * 34 + g * 16 + (lane >> 5) * 8]);
                    *reinterpret_cast<bf16x8*>(&outp[base + lane * 8]) = vv;   // 1KB/wave
                }
            }
    } else {
#pragma unroll
        for (int rt = 0; rt < 2; ++rt)
#pragma unroll
            for (int ct = 0; ct < 2; ++ct) {
                int jjB = jjBase0 + wc * 64 + ct * 32;
                float bias_v = bias[jjB + il];
#pragma unroll
                for (int r = 0; r < 16; ++r) {
                    int rl = wr * 64 + rt * 32 + ((r & 3) + 8 * (r >> 2) + 4 * hi);
                    vstage[wc * 64 + ct * 32 + il][rl] = f2bf(acc[rt][ct][r] + bias_v);
                }
            }
        __syncthreads();
        int b = rowBase >> 8, n0 = rowBase & 255;
        int h0v = jjBase0 >> 6;
#pragma unroll
        for (int q = 0; q < 8; ++q) {
            int rid = w * 8 + q;            // head(2) x jtl(4) x ks(2) x dh(2)
            int head = rid >> 4, jtl = (rid >> 2) & 3, ks = (rid >> 1) & 1, dh = rid & 1;
            int bh = b * NHEADS + h0v + head;
            int jtg = (n0 >> 5) + jtl;
            size_t base = ((((size_t)(bh * 8 + jtg) * 2 + ks) * 2 + dh) * 64) * 8;
            bf16x8 vv = *reinterpret_cast<const bf16x8*>(
                &vstage[head * 64 + dh * 32 + (lane & 31)][jtl * 32 + ks * 16 + (lane >> 5) * 8]);
            *reinterpret_cast<bf16x8*>(&v_bf_t[base + lane * 8]) = vv;   // 1KB/wave
        }
    }
}

// ---------------------------------------------------------------------------
// Kernel 3: MFMA attention, 4-way j-split, coalesced fragment loads, setprio.
// oex packed bf16 -> LDS 26.6KB (up to 6 blocks/CU by LDS); launch_bounds
// (256,4) so the regalloc keeps ~60 VGPRs (6 forced spills - round 13 lesson).
// grid = 3072 (bh x 8 rowblocks, XCD-chunked), 3 barriers.
// ---------------------------------------------------------------------------
__global__ __launch_bounds__(256, 4) void k_attn(
        const unsigned short* __restrict__ q_bf, const unsigned short* __restrict__ k_bf,
        const unsigned short* __restrict__ v_bf_t,
        const unsigned short* __restrict__ skv_bf, const unsigned short* __restrict__ svv_t_bf,
        const float* __restrict__ bias,
        float* __restrict__ wout, unsigned short* __restrict__ attn_out) {
    __shared__ __align__(16) float qs_s[32][36];
    __shared__ __align__(16) float wsum[32][48];
    __shared__ __align__(8) unsigned oex[3][32][36];   // packed bf16 O partials
    __shared__ float msum[4][32][2];
    __shared__ float bias_s[NN];

    const int bx0 = blockIdx.x;
    const int bx = (bx0 & 7) * 384 + (bx0 >> 3);    // XCD-chunked
    const int bh = bx >> 3, rowblk = bx & 7;
    const int b = bh / NHEADS, h = bh - b * NHEADS;
    const int tid = threadIdx.x;
    const int w = tid >> 6, lane = tid & 63;
    const int il = lane & 31, hi = lane >> 5;
    const int i0 = rowblk * 32;
    const int ig = i0 + il;

    bias_s[tid] = bias[b * NN + tid];
#pragma unroll
    for (int z = 0; z < 6; ++z) ((float*)wsum)[tid + z * 256] = 0.f;

    // Q fragments (coalesced: base + lane*16B)
    bf16x8 qf[4];
#pragma unroll
    for (int kt = 0; kt < 4; ++kt)
        qf[kt] = *reinterpret_cast<const bf16x8*>(
            &q_bf[((((size_t)bh * 8 + rowblk) * 4 + kt) * 64 + lane) * 8]);

    // qs = Q @ skv^T, wave 0 only
    if (w == 0) {
        f32x16 qa0 = {}, qa1 = {};
#pragma unroll
        for (int kt = 0; kt < 4; ++kt) {
            bf16x8 s0 = *reinterpret_cast<const bf16x8*>(&skv_bf[(size_t)il * 64 + kt * 16 + 8 * hi]);
            bf16x8 s1 = *reinterpret_cast<const bf16x8*>(&skv_bf[(size_t)(32 + il) * 64 + kt * 16 + 8 * hi]);
            qa0 = MFMA32(qf[kt], s0, qa0, 0, 0, 0);
            qa1 = MFMA32(qf[kt], s1, qa1, 0, 0, 0);
        }
#pragma unroll
        for (int r = 0; r < 16; ++r) {
            int ir = (r & 3) + 8 * (r >> 2) + 4 * hi;
            qs_s[ir][il] = qa0[r];
            if (il < 3) qs_s[ir][32 + il] = qa1[r];
        }
    }

    // QK^T for this wave's 64-j strip (coalesced K loads)
    f32x16 S[2] = {};
    __builtin_amdgcn_s_setprio(1);
#pragma unroll
    for (int jt = 0; jt < 2; ++jt) {
        int jtg = w * 2 + jt;
#pragma unroll
        for (int kt = 0; kt < 4; ++kt) {
            bf16x8 kf = *reinterpret_cast<const bf16x8*>(
                &k_bf[((((size_t)bh * 8 + jtg) * 4 + kt) * 64 + lane) * 8]);
            S[jt] = MFMA32(kf, qf[kt], S[jt], 0, 0, 0);
        }
    }
    __builtin_amdgcn_s_setprio(0);

    __syncthreads();   // b1: bias, qs, zeroed wsum ready

    const int jb = w * 64;
    // add struct_w (clamped qs lookup) + bias
    {
        float qlo = qs_s[il][0], qhi = qs_s[il][34];
#pragma unroll
        for (int jt = 0; jt < 2; ++jt) {
#pragma unroll
            for (int rg = 0; rg < 4; ++rg) {
                int j0 = jb + jt * 32 + rg * 8 + 4 * hi;
                float4 bv4 = *reinterpret_cast<const float4*>(&bias_s[j0]);
                float bvf[4] = {bv4.x, bv4.y, bv4.z, bv4.w};
#pragma unroll
                for (int e = 0; e < 4; ++e) {
                    int dd = j0 + e - ig;
                    float sw = (dd < -16) ? qlo : (dd > 16) ? qhi : qs_s[il][dd + 17];
                    S[jt][rg * 4 + e] += bvf[e] + sw;
                }
            }
        }
    }

    // partial softmax over this j-strip (row split lane/lane^32)
    float m = -3.4e38f;
#pragma unroll
    for (int jt = 0; jt < 2; ++jt)
#pragma unroll
        for (int r = 0; r < 16; ++r) m = fmaxf(m, S[jt][r]);
    m = fmaxf(m, __shfl_xor(m, 32));
    float sum = 0.f;
#pragma unroll
    for (int jt = 0; jt < 2; ++jt)
#pragma unroll
        for (int r = 0; r < 16; ++r) { float p = __expf(S[jt][r] - m); S[jt][r] = p; sum += p; }
    sum += __shfl_xor(sum, 32);
    if (hi == 0) { msum[w][il][0] = m; msum[w][il][1] = sum; }
    __syncthreads();   // b2: all partial (m,sum) ready

    {
        float m0 = msum[0][il][0], m1 = msum[1][il][0];
        float m2 = msum[2][il][0], m3 = msum[3][il][0];
        float M = fmaxf(fmaxf(m0, m1), fmaxf(m2, m3));
        float sumT = msum[0][il][1] * __expf(m0 - M) + msum[1][il][1] * __expf(m1 - M) +
                     msum[2][il][1] * __expf(m2 - M) + msum[3][il][1] * __expf(m3 - M);
        float scale = __expf(m - M) / sumT;
#pragma unroll
        for (int jt = 0; jt < 2; ++jt)
#pragma unroll
            for (int r = 0; r < 16; ++r) S[jt][r] *= scale;
    }

    // histogram scatter
    {
        float elo = 0.f, ehi = 0.f;
#pragma unroll
        for (int jt = 0; jt < 2; ++jt)
#pragma unroll
            for (int r = 0; r < 16; ++r) {
                int j = jb + jt * 32 + (r & 3) + 8 * (r >> 2) + 4 * hi;
                int dd = j - ig;
                float p = S[jt][r];
                if (dd < -16) elo += p;
                else if (dd > 16) ehi += p;
                else wsum[il][dd + 17] = p;
            }
        if (elo != 0.f) atomicAdd(&wsum[il][0], elo);
        if (ehi != 0.f) atomicAdd(&wsum[il][34], ehi);
    }

    // main PV (O^T) from regs (coalesced V loads)
    f32x16 O0 = {}, O1 = {};
    __builtin_amdgcn_s_setprio(1);
#pragma unroll
    for (int jt = 0; jt < 2; ++jt) {
        int jtg = w * 2 + jt;
#pragma unroll
        for (int ks = 0; ks < 2; ++ks) {
            unsigned w0 = pk2(S[jt][8 * ks + 0], S[jt][8 * ks + 1]);
            unsigned w1 = pk2(S[jt][8 * ks + 2], S[jt][8 * ks + 3]);
            unsigned w2 = pk2(S[jt][8 * ks + 4], S[jt][8 * ks + 5]);
            unsigned w3 = pk2(S[jt][8 * ks + 6], S[jt][8 * ks + 7]);
            unsigned s0 = hi ? w0 : w2, s1 = hi ? w1 : w3;
            unsigned y0 = (unsigned)__shfl_xor((int)s0, 32);
            unsigned y1 = (unsigned)__shfl_xor((int)s1, 32);
            union { bf16x8 v; unsigned u[4]; } Bf;
            Bf.u[0] = hi ? y0 : w0;
            Bf.u[1] = hi ? y1 : w1;
            Bf.u[2] = hi ? w2 : y0;
            Bf.u[3] = hi ? w3 : y1;
            bf16x8 va0 = *reinterpret_cast<const bf16x8*>(
                &v_bf_t[(((((size_t)bh * 8 + jtg) * 2 + ks) * 2 + 0) * 64 + lane) * 8]);
            bf16x8 va1 = *reinterpret_cast<const bf16x8*>(
                &v_bf_t[(((((size_t)bh * 8 + jtg) * 2 + ks) * 2 + 1) * 64 + lane) * 8]);
            O0 = MFMA32(va0, Bf.v, O0, 0, 0, 0);
            O1 = MFMA32(va1, Bf.v, O1, 0, 0, 0);
        }
    }
    __builtin_amdgcn_s_setprio(0);

    // w-write: direct f32 from S regs (after PV so V loads issue early)
#pragma unroll
    for (int jt = 0; jt < 2; ++jt) {
#pragma unroll
        for (int rg = 0; rg < 4; ++rg) {
            float4 val;
            val.x = S[jt][rg * 4 + 0];
            val.y = S[jt][rg * 4 + 1];
            val.z = S[jt][rg * 4 + 2];
            val.w = S[jt][rg * 4 + 3];
            *reinterpret_cast<float4*>(
                &wout[((size_t)(bh * NN + ig)) * NN + jb + jt * 32 + rg * 8 + 4 * hi]) = val;
        }
    }

    // waves 1-3: write partial O (packed bf16) to private slice
    if (w != 0) {
#pragma unroll
        for (int qq = 0; qq < 4; ++qq) {
            int d0 = 8 * qq + 4 * hi;
            u32x2 p0, p1;
            p0[0] = pk2(O0[4 * qq + 0], O0[4 * qq + 1]);
            p0[1] = pk2(O0[4 * qq + 2], O0[4 * qq + 3]);
            p1[0] = pk2(O1[4 * qq + 0], O1[4 * qq + 1]);
            p1[1] = pk2(O1[4 * qq + 2], O1[4 * qq + 3]);
            *reinterpret_cast<u32x2*>(&oex[w - 1][il][d0 >> 1]) = p0;
            *reinterpret_cast<u32x2*>(&oex[w - 1][il][(32 + d0) >> 1]) = p1;
        }
    }
    __syncthreads();   // b3: histogram + O partials complete

    if (w == 0) {
#pragma unroll
        for (int s = 0; s < 3; ++s) {
#pragma unroll
            for (int qq = 0; qq < 4; ++qq) {
                int d0 = 8 * qq + 4 * hi;
                u32x2 p0 = *reinterpret_cast<const u32x2*>(&oex[s][il][d0 >> 1]);
                u32x2 p1 = *reinterpret_cast<const u32x2*>(&oex[s][il][(32 + d0) >> 1]);
                O0[4 * qq + 0] += __uint_as_float((p0[0] & 0xffffu) << 16);
                O0[4 * qq + 1] += __uint_as_float(p0[0] & 0xffff0000u);
                O0[4 * qq + 2] += __uint_as_float((p0[1] & 0xffffu) << 16);
                O0[4 * qq + 3] += __uint_as_float(p0[1] & 0xffff0000u);
                O1[4 * qq + 0] += __uint_as_float((p1[0] & 0xffffu) << 16);
                O1[4 * qq + 1] += __uint_as_float(p1[0] & 0xffff0000u);
                O1[4 * qq + 2] += __uint_as_float((p1[1] & 0xffffu) << 16);
                O1[4 * qq + 3] += __uint_as_float(p1[1] & 0xffff0000u);
            }
        }

        // struct-PV: O^T += svv^T @ wsum^T
#pragma unroll
        for (int kt = 0; kt < 3; ++kt) {
            float4 a0 = *reinterpret_cast<const float4*>(&wsum[il][kt * 16 + 8 * hi]);
            float4 a1 = *reinterpret_cast<const float4*>(&wsum[il][kt * 16 + 8 * hi + 4]);
            float af[8] = {a0.x, a0.y, a0.z, a0.w, a1.x, a1.y, a1.z, a1.w};
            bf16x8 Bf = pack8(af);
            bf16x8 sa0 = *reinterpret_cast<const bf16x8*>(&svv_t_bf[(size_t)il * 48 + kt * 16 + 8 * hi]);
            bf16x8 sa1 = *reinterpret_cast<const bf16x8*>(&svv_t_bf[(size_t)(32 + il) * 48 + kt * 16 + 8 * hi]);
            O0 = MFMA32(sa0, Bf, O0, 0, 0, 0);
            O1 = MFMA32(sa1, Bf, O1, 0, 0, 0);
        }

        // attn_out (bf16): lane owns row i0+il, regs span d
#pragma unroll
        for (int qq = 0; qq < 4; ++qq) {
            int d0 = 8 * qq + 4 * hi;
            u32x2 o0, o1;
            o0[0] = pk2(O0[4 * qq + 0], O0[4 * qq + 1]);
            o0[1] = pk2(O0[4 * qq + 2], O0[4 * qq + 3]);
            o1[0] = pk2(O1[4 * qq + 0], O1[4 * qq + 1]);
            o1[1] = pk2(O1[4 * qq + 2], O1[4 * qq + 3]);
            size_t base = ((size_t)(b * NN + i0 + il)) * HH + h * 64;
            *reinterpret_cast<u32x2*>(&attn_out[base + d0]) = o0;
            *reinterpret_cast<u32x2*>(&attn_out[base + 32 + d0]) = o1;
        }
    }
}

// ---------------------------------------------------------------------------
// Kernel 4: O-projection MFMA GEMM + bias + relu -> bf16
// ---------------------------------------------------------------------------
__global__ __launch_bounds__(256) void k_ogemm(
        const unsigned short* __restrict__ Abf, const unsigned short* __restrict__ Bt,
        const float* __restrict__ bo, unsigned short* __restrict__ Cout) {
    __shared__ unsigned short Al[2][128 * 32];
    __shared__ unsigned short Bl[2][128 * 32];

    const int tid = threadIdx.x;
    const int w = tid >> 6, lane = tid & 63;
    const int il = lane & 31, hi = lane >> 5;
    const int wr = w >> 1, wc = w & 1;
    const int rowBase = blockIdx.x * 128;
    const int colBase = blockIdx.y * 128;

    f32x16 acc[2][2] = {};

    auto STAGE = [&](int buf, int k0) {
#pragma unroll
        for (int c = 0; c < 2; ++c) {
            int e = tid + c * 256;
            int row = e >> 2;
            int cb = (e & 3) << 4;
            int sc = cb ^ (((row >> 1) & 3) << 4);
            __builtin_amdgcn_global_load_lds(
                (const __attribute__((address_space(1))) unsigned int*)(Abf + (size_t)(rowBase + row) * HH + k0 + (sc >> 1)),
                (__attribute__((address_space(3))) unsigned int*)(&Al[buf][row * 32 + (cb >> 1)]), 16, 0, 0);
            __builtin_amdgcn_global_load_lds(
                (const __attribute__((address_space(1))) unsigned int*)(Bt + (size_t)(colBase + row) * HH + k0 + (sc >> 1)),
                (__attribute__((address_space(3))) unsigned int*)(&Bl[buf][row * 32 + (cb >> 1)]), 16, 0, 0);
        }
    };

    STAGE(0, 0);
    __syncthreads();
    for (int t = 0; t < 24; ++t) {
        int buf = t & 1;
        if (t < 23) STAGE(buf ^ 1, (t + 1) * 32);
#pragma unroll
        for (int ks = 0; ks < 2; ++ks) {
            bf16x8 af[2], bfr[2];
            int cb = (ks << 5) + (hi << 4);
#pragma unroll
            for (int t2 = 0; t2 < 2; ++t2) {
                int rrow = wr * 64 + t2 * 32 + il;
                af[t2] = *reinterpret_cast<const bf16x8*>(
                    &Al[buf][rrow * 32 + ((cb ^ (((rrow >> 1) & 3) << 4)) >> 1)]);
                int crow = wc * 64 + t2 * 32 + il;
                bfr[t2] = *reinterpret_cast<const bf16x8*>(
                    &Bl[buf][crow * 32 + ((cb ^ (((crow >> 1) & 3) << 4)) >> 1)]);
            }
            acc[0][0] = MFMA32(af[0], bfr[0], acc[0][0], 0, 0, 0);
            acc[0][1] = MFMA32(af[0], bfr[1], acc[0][1], 0, 0, 0);
            acc[1][0] = MFMA32(af[1], bfr[0], acc[1][0], 0, 0, 0);
            acc[1][1] = MFMA32(af[1], bfr[1], acc[1][1], 0, 0, 0);
        }
        __syncthreads();
    }

#pragma unroll
    for (int rt = 0; rt < 2; ++rt)
#pragma unroll
        for (int ct = 0; ct < 2; ++ct) {
            int col = colBase + wc * 64 + ct * 32 + il;
            float bias_v = bo[col];
#pragma unroll
            for (int r = 0; r < 16; ++r) {
                int row = rowBase + wr * 64 + rt * 32 + ((r & 3) + 8 * (r >> 2) + 4 * hi);
                Cout[(size_t)row * HH + col] = f2bf(fmaxf(acc[rt][ct][r] + bias_v, 0.f));
            }
        }
}

// ---------------------------------------------------------------------------
// Kernel 5: final LayerNorm(nodes_bf16 + proj_bf16), single-pass + shfl
// ---------------------------------------------------------------------------
__global__ __launch_bounds__(256) void k_ln(
        const unsigned short* __restrict__ nodes_bf, const unsigned short* __restrict__ proj,
        const float* __restrict__ g, const float* __restrict__ bta,
        float* __restrict__ out) {
    __shared__ float red[2][4];
    int row = blockIdx.x;
    int tid = threadIdx.x;
    int w = tid >> 6, lane = tid & 63;
    float x[3];
    float s = 0.f, s2 = 0.f;
#pragma unroll
    for (int l = 0; l < 3; ++l) {
        int c = tid + l * 256;
        x[l] = bf2f(nodes_bf[(size_t)row * HH + c]) + bf2f(proj[(size_t)row * HH + c]);
        s += x[l];
        s2 += x[l] * x[l];
    }
#pragma unroll
    for (int off = 32; off > 0; off >>= 1) {
        s += __shfl_xor(s, off);
        s2 += __shfl_xor(s2, off);
    }
    if (lane == 0) { red[0][w] = s; red[1][w] = s2; }
    __syncthreads();
    float ts = red[0][0] + red[0][1] + red[0][2] + red[0][3];
    float ts2 = red[1][0] + red[1][1] + red[1][2] + red[1][3];
    float mean = ts / HH;
    float var = ts2 / HH - mean * mean;
    float inv = rsqrtf(fmaxf(var, 0.f) + 1e-5f);
#pragma unroll
    for (int l = 0; l < 3; ++l) {
        int c = tid + l * 256;
        out[(size_t)row * HH + c] = (x[l] - mean) * inv * g[c] + bta[c];
    }
}

// ---------------------------------------------------------------------------
extern "C" void kernel_launch(void* const* d_in, const int* in_sizes, int n_in,
                              void* d_out, int out_size, void* d_ws, size_t ws_size,
                              hipStream_t stream) {
    const float* nodes     = (const float*)d_in[0];
    const float* bias      = (const float*)d_in[1];
    const float* pos_table = (const float*)d_in[3];
    const float* Wq = (const float*)d_in[4];  const float* bq = (const float*)d_in[5];
    const float* Wk = (const float*)d_in[6];  const float* bk = (const float*)d_in[7];
    const float* Wv = (const float*)d_in[8];  const float* bv = (const float*)d_in[9];
    const float* Wsk = (const float*)d_in[10]; const float* bsk = (const float*)d_in[11];
    const float* Wsv = (const float*)d_in[12]; const float* bsv = (const float*)d_in[13];
    const float* Wo = (const float*)d_in[14]; const float* bo = (const float*)d_in[15];
    const float* g_path = (const float*)d_in[16]; const float* b_path = (const float*)d_in[17];
    const float* g_norm = (const float*)d_in[18]; const float* b_norm = (const float*)d_in[19];

    float* out0 = (float*)d_out;                         // (B,N,H)
    float* wout = out0 + (size_t)BB * NN * HH;           // (B,HEADS,N,N)

    const size_t per = (size_t)BB * NN * HH;             // 6,291,456 elements
    char* p = (char*)d_ws;
    unsigned short* q_bf    = (unsigned short*)p; p += per * 2;
    unsigned short* k_bf    = (unsigned short*)p; p += per * 2;
    unsigned short* v_bf_t  = (unsigned short*)p; p += per * 2;
    unsigned short* skv_bf  = (unsigned short*)p; p += 64 * 64 * 2;
    unsigned short* svv_t   = (unsigned short*)p; p += 64 * 48 * 2;
    unsigned short* nodes_bf= (unsigned short*)p; p += per * 2;
    unsigned short* Wt      = (unsigned short*)p; p += (size_t)4 * HH * HH * 2;
    unsigned short* attn_bf = (unsigned short*)p; p += per * 2;
    unsigned short* proj_bf = v_bf_t;   // Vf dead after k_attn

    k_prep<<<6784, 256, 0, stream>>>(nodes, nodes_bf, Wq, Wk, Wv, Wo, Wt,
                                     pos_table, g_path, b_path, Wsk, bsk, Wsv, bsv,
                                     skv_bf, svv_t);

    dim3 g2(64, 18);
    k_qkv<<<g2, 256, 0, stream>>>(nodes_bf, Wt, bq, bk, bv, q_bf, k_bf, v_bf_t);

    k_attn<<<BB * NHEADS * 8, 256, 0, stream>>>(q_bf, k_bf, v_bf_t, skv_bf, svv_t, bias, wout, attn_bf);

    dim3 g4(64, 6);
    k_ogemm<<<g4, 256, 0, stream>>>(attn_bf, Wt + (size_t)3 * HH * HH, bo, proj_bf);

    k_ln<<<BB * NN, 256, 0, stream>>>(nodes_bf, proj_bf, g_norm, b_norm, out0);
}